// Round 1
// baseline (1052.714 us; speedup 1.0000x reference)
//
#include <hip/hip_runtime.h>

#define KDIM 64

// -------- Phase 1: stat0 = sigmoid(stu_W @ know_W^T), diff0 likewise; also
// initialize the SpMM accumulators with the same values (stat/diff = (x0 + s1 + s2)/3,
// division by 3 deferred to the tail kernel).
__global__ __launch_bounds__(256) void embed_sig(
    const float* __restrict__ stuW, const float* __restrict__ exerW,
    const float* __restrict__ knowW,
    float* __restrict__ stat0, float* __restrict__ stat_acc,
    float* __restrict__ diff0, float* __restrict__ diff_acc,
    int S, int E)
{
    __shared__ float kwT[64][65];   // transposed know_W, +1 pad: conflict-free
    for (int i = threadIdx.x; i < 64 * 64; i += 256) {
        int k = i >> 6, d = i & 63;
        kwT[d][k] = knowW[i];
    }
    __syncthreads();

    const int lane = threadIdx.x & 63;
    const int wid  = threadIdx.x >> 6;
    const int total = S + E;
    for (int row = blockIdx.x * 4 + wid; row < total; row += gridDim.x * 4) {
        const float* a = (row < S) ? (stuW + (size_t)row * KDIM)
                                   : (exerW + (size_t)(row - S) * KDIM);
        const float4* a4 = (const float4*)a;
        float acc = 0.f;
        #pragma unroll
        for (int d4 = 0; d4 < 16; ++d4) {
            float4 av = a4[d4];
            acc += av.x * kwT[d4 * 4 + 0][lane];
            acc += av.y * kwT[d4 * 4 + 1][lane];
            acc += av.z * kwT[d4 * 4 + 2][lane];
            acc += av.w * kwT[d4 * 4 + 3][lane];
        }
        float s = 1.f / (1.f + __expf(-acc));
        if (row < S) {
            size_t o = (size_t)row * KDIM + lane;
            stat0[o] = s;
            stat_acc[o] = s;
        } else {
            size_t o = (size_t)(row - S) * KDIM + lane;
            diff0[o] = s;
            diff_acc[o] = s;
        }
    }
}

// -------- Phase 2: out[row] += val * X[col]  (one wave per edge, lane = k)
__global__ __launch_bounds__(256) void spmm_atomic(
    const int* __restrict__ idx, const float* __restrict__ val,
    const float* __restrict__ X, float* __restrict__ out, int nnz)
{
    const int lane = threadIdx.x & 63;
    const int e = blockIdx.x * 4 + (threadIdx.x >> 6);
    if (e >= nnz) return;
    const int row = idx[e];          // idx is [2, nnz] row-major: first nnz = rows
    const int col = idx[nnz + e];
    const float v = val[e];
    atomicAdd(out + (size_t)row * KDIM + lane, v * X[(size_t)col * KDIM + lane]);
}

// -------- Phase 3: fused gather + NCD MLP. One block = 64 batch rows.
__global__ __launch_bounds__(256, 1) void tail_mlp(
    const float* __restrict__ stat_acc, const float* __restrict__ diff_acc,
    const float* __restrict__ discW,
    const float* __restrict__ W1, const float* __restrict__ b1,
    const float* __restrict__ W2, const float* __restrict__ b2,
    const float* __restrict__ W3, const float* __restrict__ b3,
    const float* __restrict__ kn, const int* __restrict__ stu_id,
    const int* __restrict__ exer_id, float* __restrict__ out, int B)
{
    __shared__ float xs[64][64];     // 16 KB
    __shared__ float h1s[64][256];   // 64 KB
    __shared__ float h2s[64][129];   // 33 KB (pad 129: phase-4 reads conflict-free)
    const int tid = threadIdx.x;
    const int b0 = blockIdx.x * 64;

    // phase 1: x = disc * (stat - diff)/3 * kn   (per wave: uniform row, coalesced k)
    for (int i = 0; i < 16; ++i) {
        int e = i * 256 + tid;
        int r = e >> 6, k = e & 63;
        int b = b0 + r;
        float x = 0.f;
        if (b < B) {
            int sid = stu_id[b], eid = exer_id[b];
            float disc = 1.f / (1.f + __expf(-discW[eid]));
            x = disc * (stat_acc[(size_t)sid * 64 + k] - diff_acc[(size_t)eid * 64 + k])
                     * (1.f / 3.f) * kn[(size_t)b * 64 + k];
        }
        xs[r][k] = x;
    }
    __syncthreads();

    // phase 2: h1 = sigmoid(x @ relu(W1) + b1); thread t owns column t (0..255)
    {
        float w1c[64];
        #pragma unroll
        for (int k = 0; k < 64; ++k) w1c[k] = fmaxf(W1[k * 256 + tid], 0.f);
        const float bb = b1[tid];
        for (int r = 0; r < 64; ++r) {
            const float4* xr = (const float4*)xs[r];
            float acc = bb;
            #pragma unroll
            for (int k4 = 0; k4 < 16; ++k4) {
                float4 xv = xr[k4];
                acc += xv.x * w1c[k4 * 4 + 0] + xv.y * w1c[k4 * 4 + 1]
                     + xv.z * w1c[k4 * 4 + 2] + xv.w * w1c[k4 * 4 + 3];
            }
            h1s[r][tid] = 1.f / (1.f + __expf(-acc));
        }
    }
    __syncthreads();

    // phase 3: h2 = sigmoid(h1 @ relu(W2) + b2); thread: col j = tid&127, rows by half
    {
        const int j = tid & 127;
        const int rg = tid >> 7;            // 0 or 1 -> rows [0..31] or [32..63]
        float acc3[32];
        #pragma unroll
        for (int r = 0; r < 32; ++r) acc3[r] = b2[j];
        for (int kc = 0; kc < 4; ++kc) {
            float w2c[64];
            #pragma unroll
            for (int i = 0; i < 64; ++i) w2c[i] = fmaxf(W2[(kc * 64 + i) * 128 + j], 0.f);
            #pragma unroll 4
            for (int r = 0; r < 32; ++r) {
                const float4* hr = (const float4*)&h1s[rg * 32 + r][kc * 64];
                float a = 0.f;
                #pragma unroll
                for (int i4 = 0; i4 < 16; ++i4) {
                    float4 hv = hr[i4];
                    a += hv.x * w2c[i4 * 4 + 0] + hv.y * w2c[i4 * 4 + 1]
                       + hv.z * w2c[i4 * 4 + 2] + hv.w * w2c[i4 * 4 + 3];
                }
                acc3[r] += a;
            }
        }
        #pragma unroll
        for (int r = 0; r < 32; ++r)
            h2s[rg * 32 + r][j] = 1.f / (1.f + __expf(-acc3[r]));
    }
    __syncthreads();

    // phase 4: out = sigmoid(h2 @ relu(W3) + b3); lane = row (pad 129 -> no conflicts)
    if (tid < 64) {
        int b = b0 + tid;
        if (b < B) {
            float acc = b3[0];
            for (int j = 0; j < 128; ++j)
                acc += h2s[tid][j] * fmaxf(W3[j], 0.f);
            out[b] = 1.f / (1.f + __expf(-acc));
        }
    }
}

extern "C" void kernel_launch(void* const* d_in, const int* in_sizes, int n_in,
                              void* d_out, int out_size, void* d_ws, size_t ws_size,
                              hipStream_t stream) {
    const float* stuW  = (const float*)d_in[0];
    const float* exerW = (const float*)d_in[1];
    const float* knowW = (const float*)d_in[2];
    const float* discW = (const float*)d_in[3];
    const float* W1 = (const float*)d_in[4];
    const float* b1 = (const float*)d_in[5];
    const float* W2 = (const float*)d_in[6];
    const float* b2 = (const float*)d_in[7];
    const float* W3 = (const float*)d_in[8];
    const float* b3 = (const float*)d_in[9];
    const int*   ui1_idx = (const int*)d_in[10];
    const float* ui1_val = (const float*)d_in[11];
    const int*   ui0_idx = (const int*)d_in[12];
    const float* ui0_val = (const float*)d_in[13];
    const int*   iu1_idx = (const int*)d_in[14];
    const float* iu1_val = (const float*)d_in[15];
    const int*   iu0_idx = (const int*)d_in[16];
    const float* iu0_val = (const float*)d_in[17];
    const float* kn      = (const float*)d_in[18];
    const int*   stu_id  = (const int*)d_in[19];
    const int*   exer_id = (const int*)d_in[20];
    float* out = (float*)d_out;

    const int S = in_sizes[0] / KDIM;
    const int E = in_sizes[1] / KDIM;
    const int B = in_sizes[19];
    const int NNZ = in_sizes[11];

    float* ws = (float*)d_ws;
    float* stat0    = ws;
    float* stat_acc = stat0    + (size_t)S * KDIM;
    float* diff0    = stat_acc + (size_t)S * KDIM;
    float* diff_acc = diff0    + (size_t)E * KDIM;

    embed_sig<<<2048, 256, 0, stream>>>(stuW, exerW, knowW,
                                        stat0, stat_acc, diff0, diff_acc, S, E);

    int spmm_blocks = (NNZ + 3) / 4;
    spmm_atomic<<<spmm_blocks, 256, 0, stream>>>(ui1_idx, ui1_val, diff0, stat_acc, NNZ);
    spmm_atomic<<<spmm_blocks, 256, 0, stream>>>(ui0_idx, ui0_val, diff0, stat_acc, NNZ);
    spmm_atomic<<<spmm_blocks, 256, 0, stream>>>(iu1_idx, iu1_val, stat0, diff_acc, NNZ);
    spmm_atomic<<<spmm_blocks, 256, 0, stream>>>(iu0_idx, iu0_val, stat0, diff_acc, NNZ);

    tail_mlp<<<(B + 63) / 64, 256, 0, stream>>>(stat_acc, diff_acc, discW,
                                                W1, b1, W2, b2, W3, b3,
                                                kn, stu_id, exer_id, out, B);
}

// Round 2
// 832.432 us; speedup vs baseline: 1.2646x; 1.2646x over previous
//
#include <hip/hip_runtime.h>

#define KDIM 64

__device__ __forceinline__ float bf16u_to_f(unsigned short u) {
    return __uint_as_float(((unsigned)u) << 16);
}
__device__ __forceinline__ unsigned short f_to_bf16u(float f) {
    unsigned b = __float_as_uint(f);
    b += 0x7FFF + ((b >> 16) & 1);          // round-to-nearest-even
    return (unsigned short)(b >> 16);
}

// -------- Phase 1: stat0 = sigmoid(stu_W @ know_W^T), diff0 likewise (bf16 out)
__global__ __launch_bounds__(256) void embed_sig(
    const float* __restrict__ stuW, const float* __restrict__ exerW,
    const float* __restrict__ knowW,
    unsigned short* __restrict__ stat0b, unsigned short* __restrict__ diff0b,
    int S, int E)
{
    __shared__ float kwT[64][65];   // transposed know_W, +1 pad: conflict-free
    for (int i = threadIdx.x; i < 64 * 64; i += 256) {
        int k = i >> 6, d = i & 63;
        kwT[d][k] = knowW[i];
    }
    __syncthreads();

    const int lane = threadIdx.x & 63;
    const int row = blockIdx.x * 4 + (threadIdx.x >> 6);
    if (row >= S + E) return;
    const float* a = (row < S) ? (stuW + (size_t)row * KDIM)
                               : (exerW + (size_t)(row - S) * KDIM);
    const float4* a4 = (const float4*)a;
    float acc = 0.f;
    #pragma unroll
    for (int d4 = 0; d4 < 16; ++d4) {
        float4 av = a4[d4];
        acc += av.x * kwT[d4 * 4 + 0][lane];
        acc += av.y * kwT[d4 * 4 + 1][lane];
        acc += av.z * kwT[d4 * 4 + 2][lane];
        acc += av.w * kwT[d4 * 4 + 3][lane];
    }
    float s = 1.f / (1.f + __expf(-acc));
    if (row < S) stat0b[(size_t)row * KDIM + lane] = f_to_bf16u(s);
    else         diff0b[(size_t)(row - S) * KDIM + lane] = f_to_bf16u(s);
}

// -------- CSR build step 1: histogram rows
__global__ __launch_bounds__(256) void count_rows(
    const int* __restrict__ idx, int* __restrict__ cnt, int base, int nnz)
{
    int e = blockIdx.x * 256 + threadIdx.x;
    if (e < nnz) atomicAdd(&cnt[base + idx[e]], 1);
}

// -------- CSR build step 2a: per-1024-chunk sums
__global__ __launch_bounds__(256) void scan_partial(
    const int* __restrict__ cnt, int* __restrict__ bsum, int n)
{
    __shared__ int red[256];
    int b = blockIdx.x;
    int s = 0;
    for (int i = threadIdx.x; i < 1024; i += 256) {
        int g = b * 1024 + i;
        if (g < n) s += cnt[g];
    }
    red[threadIdx.x] = s;
    __syncthreads();
    for (int o = 128; o > 0; o >>= 1) {
        if (threadIdx.x < o) red[threadIdx.x] += red[threadIdx.x + o];
        __syncthreads();
    }
    if (threadIdx.x == 0) bsum[b] = red[0];
}

// -------- CSR build step 2b: scan the chunk sums (nb <= 256)
__global__ __launch_bounds__(256) void scan_bsum(
    int* __restrict__ bsum, int nb, int* __restrict__ ptr, int n)
{
    __shared__ int s[256];
    int t = threadIdx.x;
    int v = (t < nb) ? bsum[t] : 0;
    s[t] = v;
    __syncthreads();
    for (int o = 1; o < 256; o <<= 1) {
        int add = (t >= o) ? s[t - o] : 0;
        __syncthreads();
        s[t] += add;
        __syncthreads();
    }
    if (t < nb) bsum[t] = s[t] - v;       // exclusive
    if (t == nb - 1) ptr[n] = s[t];       // grand total
}

// -------- CSR build step 2c: final exclusive scan -> ptr, and cursor copy
__global__ __launch_bounds__(256) void scan_final(
    const int* __restrict__ cnt, const int* __restrict__ bsum,
    int* __restrict__ ptr, int* __restrict__ cursor, int n)
{
    __shared__ int ts[256];
    int b = blockIdx.x, t = threadIdx.x;
    int g0 = b * 1024 + t * 4;
    int v[4]; int s = 0;
    #pragma unroll
    for (int i = 0; i < 4; ++i) {
        int g = g0 + i;
        v[i] = (g < n) ? cnt[g] : 0;
        s += v[i];
    }
    ts[t] = s;
    __syncthreads();
    int mine = s;
    for (int o = 1; o < 256; o <<= 1) {
        int add = (t >= o) ? ts[t - o] : 0;
        __syncthreads();
        ts[t] += add;
        __syncthreads();
    }
    int off = bsum[b] + ts[t] - mine;     // exclusive offset of this thread's 4
    #pragma unroll
    for (int i = 0; i < 4; ++i) {
        int g = g0 + i;
        if (g < n) { ptr[g] = off; cursor[g] = off; }
        off += v[i];
    }
}

// -------- CSR build step 3: scatter packed (col:u16 | val:bf16) records
__global__ __launch_bounds__(256) void scatter_edges(
    const int* __restrict__ idx, const float* __restrict__ val,
    int* __restrict__ cursor, unsigned* __restrict__ edges, int base, int nnz)
{
    int e = blockIdx.x * 256 + threadIdx.x;
    if (e >= nnz) return;
    int row = idx[e], col = idx[nnz + e];
    unsigned short vb = f_to_bf16u(val[e]);
    int pos = atomicAdd(&cursor[base + row], 1);
    edges[pos] = ((unsigned)col << 16) | (unsigned)vb;
}

// -------- Pull SpMM: one wave per output row; no data-path atomics.
// statF[w] = stat0[w] + sum(ui1 row w) + sum(ui0 row w)   (/3 deferred to tail)
__global__ __launch_bounds__(256) void pull_spmm(
    const unsigned short* __restrict__ stat0b, const unsigned short* __restrict__ diff0b,
    const int* __restrict__ ptr, const unsigned* __restrict__ edges,
    float* __restrict__ statF, float* __restrict__ diffF, int S, int E)
{
    const int w = blockIdx.x * 4 + (threadIdx.x >> 6);
    const int lane = threadIdx.x & 63;
    if (w >= S + E) return;

    const unsigned short* X;
    const unsigned short* x0;
    float* out;
    int row, i0, i1;
    if (w < S) { row = w;     X = diff0b; x0 = stat0b; out = statF; i0 = row;         i1 = S + row; }
    else       { row = w - S; X = stat0b; x0 = diff0b; out = diffF; i0 = 2 * S + row; i1 = 2 * S + E + row; }

    float acc = bf16u_to_f(x0[(size_t)row * KDIM + lane]);
    #pragma unroll
    for (int r = 0; r < 2; ++r) {
        int e  = ptr[r ? i1 : i0];
        int ee = ptr[(r ? i1 : i0) + 1];
        while (e < ee) {
            int m = ee - e; if (m > 64) m = 64;
            unsigned u = (lane < m) ? edges[e + lane] : 0;  // coalesced batch
            #pragma unroll 4
            for (int j = 0; j < m; ++j) {
                unsigned uj = __shfl(u, j);
                float v = __uint_as_float((uj & 0xFFFFu) << 16);
                acc = fmaf(v, bf16u_to_f(X[((size_t)(uj >> 16)) * KDIM + lane]), acc);
            }
            e += m;
        }
    }
    out[(size_t)row * KDIM + lane] = acc;
}

// -------- Fused gather + NCD MLP. One block = 64 batch rows.
__global__ __launch_bounds__(256, 1) void tail_mlp(
    const float* __restrict__ statF, const float* __restrict__ diffF,
    const float* __restrict__ discW,
    const float* __restrict__ W1, const float* __restrict__ b1,
    const float* __restrict__ W2, const float* __restrict__ b2,
    const float* __restrict__ W3, const float* __restrict__ b3,
    const float* __restrict__ kn, const int* __restrict__ stu_id,
    const int* __restrict__ exer_id, float* __restrict__ out, int B)
{
    __shared__ float xs[64][64];     // 16 KB
    __shared__ float h1s[64][256];   // 64 KB
    __shared__ float h2s[64][129];   // 33 KB
    const int tid = threadIdx.x;
    const int b0 = blockIdx.x * 64;

    for (int i = 0; i < 16; ++i) {
        int e = i * 256 + tid;
        int r = e >> 6, k = e & 63;
        int b = b0 + r;
        float x = 0.f;
        if (b < B) {
            int sid = stu_id[b], eid = exer_id[b];
            float disc = 1.f / (1.f + __expf(-discW[eid]));
            x = disc * (statF[(size_t)sid * 64 + k] - diffF[(size_t)eid * 64 + k])
                     * (1.f / 3.f) * kn[(size_t)b * 64 + k];
        }
        xs[r][k] = x;
    }
    __syncthreads();

    {   // h1 = sigmoid(x @ relu(W1) + b1); thread t owns column t
        float w1c[64];
        #pragma unroll
        for (int k = 0; k < 64; ++k) w1c[k] = fmaxf(W1[k * 256 + tid], 0.f);
        const float bb = b1[tid];
        for (int r = 0; r < 64; ++r) {
            const float4* xr = (const float4*)xs[r];
            float acc = bb;
            #pragma unroll
            for (int k4 = 0; k4 < 16; ++k4) {
                float4 xv = xr[k4];
                acc += xv.x * w1c[k4 * 4 + 0] + xv.y * w1c[k4 * 4 + 1]
                     + xv.z * w1c[k4 * 4 + 2] + xv.w * w1c[k4 * 4 + 3];
            }
            h1s[r][tid] = 1.f / (1.f + __expf(-acc));
        }
    }
    __syncthreads();

    {   // h2 = sigmoid(h1 @ relu(W2) + b2)
        const int j = tid & 127;
        const int rg = tid >> 7;
        float acc3[32];
        #pragma unroll
        for (int r = 0; r < 32; ++r) acc3[r] = b2[j];
        for (int kc = 0; kc < 4; ++kc) {
            float w2c[64];
            #pragma unroll
            for (int i = 0; i < 64; ++i) w2c[i] = fmaxf(W2[(kc * 64 + i) * 128 + j], 0.f);
            #pragma unroll 4
            for (int r = 0; r < 32; ++r) {
                const float4* hr = (const float4*)&h1s[rg * 32 + r][kc * 64];
                float a = 0.f;
                #pragma unroll
                for (int i4 = 0; i4 < 16; ++i4) {
                    float4 hv = hr[i4];
                    a += hv.x * w2c[i4 * 4 + 0] + hv.y * w2c[i4 * 4 + 1]
                       + hv.z * w2c[i4 * 4 + 2] + hv.w * w2c[i4 * 4 + 3];
                }
                acc3[r] += a;
            }
        }
        #pragma unroll
        for (int r = 0; r < 32; ++r)
            h2s[rg * 32 + r][j] = 1.f / (1.f + __expf(-acc3[r]));
    }
    __syncthreads();

    if (tid < 64) {
        int b = b0 + tid;
        if (b < B) {
            float acc = b3[0];
            for (int j = 0; j < 128; ++j)
                acc += h2s[tid][j] * fmaxf(W3[j], 0.f);
            out[b] = 1.f / (1.f + __expf(-acc));
        }
    }
}

extern "C" void kernel_launch(void* const* d_in, const int* in_sizes, int n_in,
                              void* d_out, int out_size, void* d_ws, size_t ws_size,
                              hipStream_t stream) {
    const float* stuW  = (const float*)d_in[0];
    const float* exerW = (const float*)d_in[1];
    const float* knowW = (const float*)d_in[2];
    const float* discW = (const float*)d_in[3];
    const float* W1 = (const float*)d_in[4];
    const float* b1 = (const float*)d_in[5];
    const float* W2 = (const float*)d_in[6];
    const float* b2 = (const float*)d_in[7];
    const float* W3 = (const float*)d_in[8];
    const float* b3 = (const float*)d_in[9];
    const int*   ui1_idx = (const int*)d_in[10];
    const float* ui1_val = (const float*)d_in[11];
    const int*   ui0_idx = (const int*)d_in[12];
    const float* ui0_val = (const float*)d_in[13];
    const int*   iu1_idx = (const int*)d_in[14];
    const float* iu1_val = (const float*)d_in[15];
    const int*   iu0_idx = (const int*)d_in[16];
    const float* iu0_val = (const float*)d_in[17];
    const float* kn      = (const float*)d_in[18];
    const int*   stu_id  = (const int*)d_in[19];
    const int*   exer_id = (const int*)d_in[20];
    float* out = (float*)d_out;

    const int S = in_sizes[0] / KDIM;
    const int E = in_sizes[1] / KDIM;
    const int B = in_sizes[19];
    const int n1 = in_sizes[11], n0 = in_sizes[13];
    const int m1 = in_sizes[15], m0 = in_sizes[17];
    const int n_cnt = 2 * S + 2 * E;
    const int nb = (n_cnt + 1023) / 1024;       // <= 256 by construction

    char* p = (char*)d_ws;
    unsigned short* stat0b = (unsigned short*)p; p += (size_t)S * KDIM * 2;
    unsigned short* diff0b = (unsigned short*)p; p += (size_t)E * KDIM * 2;
    float* statF = (float*)p;                    p += (size_t)S * KDIM * 4;
    float* diffF = (float*)p;                    p += (size_t)E * KDIM * 4;
    int* cnt    = (int*)p;                       p += (size_t)n_cnt * 4;
    int* ptr    = (int*)p;                       p += (size_t)(n_cnt + 1) * 4;
    int* cursor = (int*)p;                       p += (size_t)n_cnt * 4;
    int* bsum   = (int*)p;                       p += 1024;
    unsigned* edges = (unsigned*)p;              // (n1+n0+m1+m0)*4 bytes

    hipMemsetAsync(cnt, 0, (size_t)n_cnt * 4, stream);

    embed_sig<<<(S + E + 3) / 4, 256, 0, stream>>>(stuW, exerW, knowW,
                                                   stat0b, diff0b, S, E);

    count_rows<<<(n1 + 255) / 256, 256, 0, stream>>>(ui1_idx, cnt, 0, n1);
    count_rows<<<(n0 + 255) / 256, 256, 0, stream>>>(ui0_idx, cnt, S, n0);
    count_rows<<<(m1 + 255) / 256, 256, 0, stream>>>(iu1_idx, cnt, 2 * S, m1);
    count_rows<<<(m0 + 255) / 256, 256, 0, stream>>>(iu0_idx, cnt, 2 * S + E, m0);

    scan_partial<<<nb, 256, 0, stream>>>(cnt, bsum, n_cnt);
    scan_bsum<<<1, 256, 0, stream>>>(bsum, nb, ptr, n_cnt);
    scan_final<<<nb, 256, 0, stream>>>(cnt, bsum, ptr, cursor, n_cnt);

    scatter_edges<<<(n1 + 255) / 256, 256, 0, stream>>>(ui1_idx, ui1_val, cursor, edges, 0, n1);
    scatter_edges<<<(n0 + 255) / 256, 256, 0, stream>>>(ui0_idx, ui0_val, cursor, edges, S, n0);
    scatter_edges<<<(m1 + 255) / 256, 256, 0, stream>>>(iu1_idx, iu1_val, cursor, edges, 2 * S, m1);
    scatter_edges<<<(m0 + 255) / 256, 256, 0, stream>>>(iu0_idx, iu0_val, cursor, edges, 2 * S + E, m0);

    pull_spmm<<<(S + E + 3) / 4, 256, 0, stream>>>(stat0b, diff0b, ptr, edges,
                                                   statF, diffF, S, E);

    tail_mlp<<<(B + 63) / 64, 256, 0, stream>>>(statF, diffF, discW,
                                                W1, b1, W2, b2, W3, b3,
                                                kn, stu_id, exer_id, out, B);
}

// Round 3
// 685.562 us; speedup vs baseline: 1.5355x; 1.2142x over previous
//
#include <hip/hip_runtime.h>

#define KDIM 64

__device__ __forceinline__ float bf16u_to_f(unsigned short u) {
    return __uint_as_float(((unsigned)u) << 16);
}
__device__ __forceinline__ float bf16lo(unsigned u) {
    return __uint_as_float(u << 16);
}
__device__ __forceinline__ float bf16hi(unsigned u) {
    return __uint_as_float(u & 0xFFFF0000u);
}
__device__ __forceinline__ unsigned short f_to_bf16u(float f) {
    unsigned b = __float_as_uint(f);
    b += 0x7FFF + ((b >> 16) & 1);          // round-to-nearest-even
    return (unsigned short)(b >> 16);
}

// -------- Phase 1: stat0 = sigmoid(stu_W @ know_W^T), diff0 likewise (bf16 out)
__global__ __launch_bounds__(256) void embed_sig(
    const float* __restrict__ stuW, const float* __restrict__ exerW,
    const float* __restrict__ knowW,
    unsigned short* __restrict__ stat0b, unsigned short* __restrict__ diff0b,
    int S, int E)
{
    __shared__ float kwT[64][65];
    for (int i = threadIdx.x; i < 64 * 64; i += 256) {
        int k = i >> 6, d = i & 63;
        kwT[d][k] = knowW[i];
    }
    __syncthreads();

    const int lane = threadIdx.x & 63;
    const int row = blockIdx.x * 4 + (threadIdx.x >> 6);
    if (row >= S + E) return;
    const float* a = (row < S) ? (stuW + (size_t)row * KDIM)
                               : (exerW + (size_t)(row - S) * KDIM);
    const float4* a4 = (const float4*)a;
    float acc = 0.f;
    #pragma unroll
    for (int d4 = 0; d4 < 16; ++d4) {
        float4 av = a4[d4];
        acc += av.x * kwT[d4 * 4 + 0][lane];
        acc += av.y * kwT[d4 * 4 + 1][lane];
        acc += av.z * kwT[d4 * 4 + 2][lane];
        acc += av.w * kwT[d4 * 4 + 3][lane];
    }
    float s = 1.f / (1.f + __expf(-acc));
    if (row < S) stat0b[(size_t)row * KDIM + lane] = f_to_bf16u(s);
    else         diff0b[(size_t)(row - S) * KDIM + lane] = f_to_bf16u(s);
}

// -------- CSR build step 1: histogram rows over all 4 edge lists.
// Row space: [0,S) = student rows (ui1 ∪ ui0), [S,S+E) = exercise rows (iu1 ∪ iu0).
__global__ __launch_bounds__(256) void count_all(
    const int* __restrict__ i1, const int* __restrict__ i0,
    const int* __restrict__ j1, const int* __restrict__ j0,
    int n1, int n0, int m1, int m0, int S, int* __restrict__ cnt)
{
    int e = blockIdx.x * 256 + threadIdx.x;
    int t = n1 + n0 + m1 + m0;
    if (e >= t) return;
    int r;
    if (e < n1)                r = i1[e];
    else if (e < n1 + n0)      r = i0[e - n1];
    else if (e < n1 + n0 + m1) r = S + j1[e - n1 - n0];
    else                       r = S + j0[e - n1 - n0 - m1];
    atomicAdd(&cnt[r], 1);
}

// -------- CSR build step 2a: per-1024-chunk sums
__global__ __launch_bounds__(256) void scan_partial(
    const int* __restrict__ cnt, int* __restrict__ bsum, int n)
{
    __shared__ int red[256];
    int b = blockIdx.x;
    int s = 0;
    for (int i = threadIdx.x; i < 1024; i += 256) {
        int g = b * 1024 + i;
        if (g < n) s += cnt[g];
    }
    red[threadIdx.x] = s;
    __syncthreads();
    for (int o = 128; o > 0; o >>= 1) {
        if (threadIdx.x < o) red[threadIdx.x] += red[threadIdx.x + o];
        __syncthreads();
    }
    if (threadIdx.x == 0) bsum[b] = red[0];
}

// -------- CSR build step 2b: scan the chunk sums (nb <= 256)
__global__ __launch_bounds__(256) void scan_bsum(
    int* __restrict__ bsum, int nb, int* __restrict__ ptr, int n)
{
    __shared__ int s[256];
    int t = threadIdx.x;
    int v = (t < nb) ? bsum[t] : 0;
    s[t] = v;
    __syncthreads();
    for (int o = 1; o < 256; o <<= 1) {
        int add = (t >= o) ? s[t - o] : 0;
        __syncthreads();
        s[t] += add;
        __syncthreads();
    }
    if (t < nb) bsum[t] = s[t] - v;       // exclusive
    if (t == nb - 1) ptr[n] = s[t];       // grand total
}

// -------- CSR build step 2c: final exclusive scan -> ptr, cursor
__global__ __launch_bounds__(256) void scan_final(
    const int* __restrict__ cnt, const int* __restrict__ bsum,
    int* __restrict__ ptr, int* __restrict__ cursor, int n)
{
    __shared__ int ts[256];
    int b = blockIdx.x, t = threadIdx.x;
    int g0 = b * 1024 + t * 4;
    int v[4]; int s = 0;
    #pragma unroll
    for (int i = 0; i < 4; ++i) {
        int g = g0 + i;
        v[i] = (g < n) ? cnt[g] : 0;
        s += v[i];
    }
    ts[t] = s;
    __syncthreads();
    int mine = s;
    for (int o = 1; o < 256; o <<= 1) {
        int add = (t >= o) ? ts[t - o] : 0;
        __syncthreads();
        ts[t] += add;
        __syncthreads();
    }
    int off = bsum[b] + ts[t] - mine;
    #pragma unroll
    for (int i = 0; i < 4; ++i) {
        int g = g0 + i;
        if (g < n) { ptr[g] = off; cursor[g] = off; }
        off += v[i];
    }
}

// -------- CSR build step 3: scatter packed (col:u16 | val:bf16) records
__global__ __launch_bounds__(256) void scatter_all(
    const int* __restrict__ i1, const float* __restrict__ v1,
    const int* __restrict__ i0, const float* __restrict__ v0,
    const int* __restrict__ j1, const float* __restrict__ w1,
    const int* __restrict__ j0, const float* __restrict__ w0,
    int n1, int n0, int m1, int m0, int S,
    int* __restrict__ cursor, unsigned* __restrict__ edges)
{
    int e = blockIdx.x * 256 + threadIdx.x;
    int t = n1 + n0 + m1 + m0;
    if (e >= t) return;
    int r, col; float v;
    if (e < n1)                { int le = e;                r = i1[le];     col = i1[n1 + le]; v = v1[le]; }
    else if (e < n1 + n0)      { int le = e - n1;           r = i0[le];     col = i0[n0 + le]; v = v0[le]; }
    else if (e < n1 + n0 + m1) { int le = e - n1 - n0;      r = S + j1[le]; col = j1[m1 + le]; v = w1[le]; }
    else                       { int le = e - n1 - n0 - m1; r = S + j0[le]; col = j0[m0 + le]; v = w0[le]; }
    int pos = atomicAdd(&cursor[r], 1);
    edges[pos] = ((unsigned)col << 16) | (unsigned)f_to_bf16u(v);
}

// -------- Pull SpMM: one wave per output row; 4 edges processed per iteration.
// Lane split: g = lane>>4 selects edge within quad, s = lane&15 covers k = 4s..4s+3.
__global__ __launch_bounds__(256) void pull_spmm(
    const unsigned short* __restrict__ stat0b, const unsigned short* __restrict__ diff0b,
    const int* __restrict__ ptr, const unsigned* __restrict__ edges,
    float* __restrict__ statF, float* __restrict__ diffF, int S, int E)
{
    const int w = blockIdx.x * 4 + (threadIdx.x >> 6);
    if (w >= S + E) return;
    const int lane = threadIdx.x & 63;
    const int g = lane >> 4;
    const int s = lane & 15;

    const unsigned short* X  = (w < S) ? diff0b : stat0b;   // gathered table
    const unsigned short* x0 = (w < S) ? stat0b : diff0b;   // self term
    float* outp = (w < S) ? statF : diffF;
    const int row = (w < S) ? w : w - S;

    float4 acc = make_float4(0.f, 0.f, 0.f, 0.f);

    int e = ptr[w], ee = ptr[w + 1];
    while (e < ee) {
        int m = ee - e; if (m > 64) m = 64;
        unsigned u = (lane < m) ? edges[e + lane] : 0u;     // coalesced batch
        int iters = (m + 3) >> 2;
        #pragma unroll 4
        for (int jj = 0; jj < iters; ++jj) {
            unsigned uj = __shfl(u, jj * 4 + g);            // 0-word => col 0, val 0: harmless
            float v = __uint_as_float((uj & 0xFFFFu) << 16);
            ushort4 xv = *((const ushort4*)(X + (((size_t)(uj >> 16)) << 6)) + s);
            acc.x = fmaf(v, bf16u_to_f(xv.x), acc.x);
            acc.y = fmaf(v, bf16u_to_f(xv.y), acc.y);
            acc.z = fmaf(v, bf16u_to_f(xv.z), acc.z);
            acc.w = fmaf(v, bf16u_to_f(xv.w), acc.w);
        }
        e += m;
    }

    // combine the 4 edge-groups (lane bits 4,5)
    acc.x += __shfl_xor(acc.x, 16); acc.x += __shfl_xor(acc.x, 32);
    acc.y += __shfl_xor(acc.y, 16); acc.y += __shfl_xor(acc.y, 32);
    acc.z += __shfl_xor(acc.z, 16); acc.z += __shfl_xor(acc.z, 32);
    acc.w += __shfl_xor(acc.w, 16); acc.w += __shfl_xor(acc.w, 32);

    if (g == 0) {
        ushort4 x0v = *((const ushort4*)(x0 + ((size_t)row << 6)) + s);
        acc.x += bf16u_to_f(x0v.x);
        acc.y += bf16u_to_f(x0v.y);
        acc.z += bf16u_to_f(x0v.z);
        acc.w += bf16u_to_f(x0v.w);
        *((float4*)(outp + ((size_t)row << 6)) + s) = acc;
    }
}

// -------- Fused gather + NCD MLP. One block = 64 batch rows. bf16 h-tiles.
__global__ __launch_bounds__(256, 1) void tail_mlp(
    const float* __restrict__ statF, const float* __restrict__ diffF,
    const float* __restrict__ discW,
    const float* __restrict__ W1, const float* __restrict__ b1,
    const float* __restrict__ W2, const float* __restrict__ b2,
    const float* __restrict__ W3, const float* __restrict__ b3,
    const float* __restrict__ kn, const int* __restrict__ stu_id,
    const int* __restrict__ exer_id, float* __restrict__ out, int B)
{
    __shared__ float xs[64][64];              // 16 KB
    __shared__ unsigned short h1s[64][256];   // 32 KB (bf16)
    __shared__ unsigned short h2s[64][132];   // 16.5 KB (bf16, pad 132)
    const int tid = threadIdx.x;
    const int b0 = blockIdx.x * 64;

    for (int i = 0; i < 16; ++i) {
        int e = i * 256 + tid;
        int r = e >> 6, k = e & 63;
        int b = b0 + r;
        float x = 0.f;
        if (b < B) {
            int sid = stu_id[b], eid = exer_id[b];
            float disc = 1.f / (1.f + __expf(-discW[eid]));
            x = disc * (statF[(size_t)sid * 64 + k] - diffF[(size_t)eid * 64 + k])
                     * (1.f / 3.f) * kn[(size_t)b * 64 + k];
        }
        xs[r][k] = x;
    }
    __syncthreads();

    {   // h1 = sigmoid(x @ relu(W1) + b1); thread t owns column t
        float w1c[64];
        #pragma unroll
        for (int k = 0; k < 64; ++k) w1c[k] = fmaxf(W1[k * 256 + tid], 0.f);
        const float bb = b1[tid];
        for (int r = 0; r < 64; ++r) {
            const float4* xr = (const float4*)xs[r];
            float acc = bb;
            #pragma unroll
            for (int k4 = 0; k4 < 16; ++k4) {
                float4 xv = xr[k4];
                acc += xv.x * w1c[k4 * 4 + 0] + xv.y * w1c[k4 * 4 + 1]
                     + xv.z * w1c[k4 * 4 + 2] + xv.w * w1c[k4 * 4 + 3];
            }
            h1s[r][tid] = f_to_bf16u(1.f / (1.f + __expf(-acc)));
        }
    }
    __syncthreads();

    {   // h2 = sigmoid(h1 @ relu(W2) + b2)
        const int j = tid & 127;
        const int rg = tid >> 7;
        float acc3[32];
        #pragma unroll
        for (int r = 0; r < 32; ++r) acc3[r] = b2[j];
        for (int kc = 0; kc < 4; ++kc) {
            float w2c[64];
            #pragma unroll
            for (int i = 0; i < 64; ++i) w2c[i] = fmaxf(W2[(kc * 64 + i) * 128 + j], 0.f);
            #pragma unroll 4
            for (int r = 0; r < 32; ++r) {
                const uint4* hr = (const uint4*)&h1s[rg * 32 + r][kc * 64];
                float a = 0.f;
                #pragma unroll
                for (int i4 = 0; i4 < 8; ++i4) {   // 8 × uint4 = 64 bf16
                    uint4 hv = hr[i4];
                    a = fmaf(bf16lo(hv.x), w2c[i4 * 8 + 0], a);
                    a = fmaf(bf16hi(hv.x), w2c[i4 * 8 + 1], a);
                    a = fmaf(bf16lo(hv.y), w2c[i4 * 8 + 2], a);
                    a = fmaf(bf16hi(hv.y), w2c[i4 * 8 + 3], a);
                    a = fmaf(bf16lo(hv.z), w2c[i4 * 8 + 4], a);
                    a = fmaf(bf16hi(hv.z), w2c[i4 * 8 + 5], a);
                    a = fmaf(bf16lo(hv.w), w2c[i4 * 8 + 6], a);
                    a = fmaf(bf16hi(hv.w), w2c[i4 * 8 + 7], a);
                }
                acc3[r] += a;
            }
        }
        #pragma unroll
        for (int r = 0; r < 32; ++r)
            h2s[rg * 32 + r][j] = f_to_bf16u(1.f / (1.f + __expf(-acc3[r])));
    }
    __syncthreads();

    if (tid < 64) {
        int b = b0 + tid;
        if (b < B) {
            float acc = b3[0];
            const unsigned* h2r = (const unsigned*)&h2s[tid][0];
            for (int jj = 0; jj < 64; ++jj) {
                unsigned hv = h2r[jj];
                acc += bf16lo(hv) * fmaxf(W3[jj * 2 + 0], 0.f)
                     + bf16hi(hv) * fmaxf(W3[jj * 2 + 1], 0.f);
            }
            out[b] = 1.f / (1.f + __expf(-acc));
        }
    }
}

extern "C" void kernel_launch(void* const* d_in, const int* in_sizes, int n_in,
                              void* d_out, int out_size, void* d_ws, size_t ws_size,
                              hipStream_t stream) {
    const float* stuW  = (const float*)d_in[0];
    const float* exerW = (const float*)d_in[1];
    const float* knowW = (const float*)d_in[2];
    const float* discW = (const float*)d_in[3];
    const float* W1 = (const float*)d_in[4];
    const float* b1 = (const float*)d_in[5];
    const float* W2 = (const float*)d_in[6];
    const float* b2 = (const float*)d_in[7];
    const float* W3 = (const float*)d_in[8];
    const float* b3 = (const float*)d_in[9];
    const int*   ui1_idx = (const int*)d_in[10];
    const float* ui1_val = (const float*)d_in[11];
    const int*   ui0_idx = (const int*)d_in[12];
    const float* ui0_val = (const float*)d_in[13];
    const int*   iu1_idx = (const int*)d_in[14];
    const float* iu1_val = (const float*)d_in[15];
    const int*   iu0_idx = (const int*)d_in[16];
    const float* iu0_val = (const float*)d_in[17];
    const float* kn      = (const float*)d_in[18];
    const int*   stu_id  = (const int*)d_in[19];
    const int*   exer_id = (const int*)d_in[20];
    float* out = (float*)d_out;

    const int S = in_sizes[0] / KDIM;
    const int E = in_sizes[1] / KDIM;
    const int B = in_sizes[19];
    const int n1 = in_sizes[11], n0 = in_sizes[13];
    const int m1 = in_sizes[15], m0 = in_sizes[17];
    const int ntot = n1 + n0 + m1 + m0;
    const int n_rows = S + E;                   // merged row space
    const int nb = (n_rows + 1023) / 1024;      // <= 256

    char* p = (char*)d_ws;
    unsigned short* stat0b = (unsigned short*)p; p += (size_t)S * KDIM * 2;
    unsigned short* diff0b = (unsigned short*)p; p += (size_t)E * KDIM * 2;
    float* statF = (float*)p;                    p += (size_t)S * KDIM * 4;
    float* diffF = (float*)p;                    p += (size_t)E * KDIM * 4;
    int* cnt    = (int*)p;                       p += (size_t)n_rows * 4;
    int* ptr    = (int*)p;                       p += (size_t)(n_rows + 1) * 4;
    int* cursor = (int*)p;                       p += (size_t)n_rows * 4;
    int* bsum   = (int*)p;                       p += 1024;
    unsigned* edges = (unsigned*)p;              // ntot * 4 bytes

    hipMemsetAsync(cnt, 0, (size_t)n_rows * 4, stream);

    embed_sig<<<(S + E + 3) / 4, 256, 0, stream>>>(stuW, exerW, knowW,
                                                   stat0b, diff0b, S, E);

    count_all<<<(ntot + 255) / 256, 256, 0, stream>>>(ui1_idx, ui0_idx, iu1_idx, iu0_idx,
                                                      n1, n0, m1, m0, S, cnt);

    scan_partial<<<nb, 256, 0, stream>>>(cnt, bsum, n_rows);
    scan_bsum<<<1, 256, 0, stream>>>(bsum, nb, ptr, n_rows);
    scan_final<<<nb, 256, 0, stream>>>(cnt, bsum, ptr, cursor, n_rows);

    scatter_all<<<(ntot + 255) / 256, 256, 0, stream>>>(
        ui1_idx, ui1_val, ui0_idx, ui0_val, iu1_idx, iu1_val, iu0_idx, iu0_val,
        n1, n0, m1, m0, S, cursor, edges);

    pull_spmm<<<(S + E + 3) / 4, 256, 0, stream>>>(stat0b, diff0b, ptr, edges,
                                                   statF, diffF, S, E);

    tail_mlp<<<(B + 63) / 64, 256, 0, stream>>>(statF, diffF, discW,
                                                W1, b1, W2, b2, W3, b3,
                                                kn, stu_id, exer_id, out, B);
}